// Round 10
// baseline (37.471 us; speedup 1.0000x reference)
//
#include <hip/hip_runtime.h>
#include <hip/hip_bf16.h>
#include <math.h>

#define BB 64
#define LL 512
#define HH 768
#define SS 32
#define MM 2048
#define EPS_LN 1e-12f
#define EPS_COS 1e-8f

#define NKS 12                  // k-steps of 64 (i8 MFMA)
#define NGB 384                 // gemm blocks (64m x 64n tiles: 32 x 12)
#define CH_PER_G (NKS * 2 * 64) // int4v chunks per row-group: 1536
#define A_RG (MM / 16)          // 128
#define B_RG (HH / 16)          // 48
#define LDST 772                // LDS row stride (floats)
#define SEG_SLICES 8
#define SEG_BLK (BB * SEG_SLICES)   // 512

#define SCALE_X 4096.0f         // 2^12
#define SCALE_W 131072.0f       // 2^17
#define INV_SC  1.8626451e-9f   // 2^-29

typedef __attribute__((ext_vector_type(4))) int int4v;

static __device__ inline void quant(float x, float scale,
                                    signed char& hi, signed char& lo) {
    int v = (int)rintf(x * scale);
    v = max(-32639, min(32639, v));
    const signed char l8 = (signed char)(v & 0xFF);
    hi = (signed char)((v - (int)l8) >> 8);
    lo = l8;
}

// K1: bid [0,176): quant-split gp/W row-groups (throughput-bound, dispatch first);
//     bid [176,688): segmean partial sums (latency-bound, overlaps splits).
// Chunk layout (int4v units): rg*1536 + ks*128 + plane*64 + lane; lane l holds
// row rg*16+(l&15), k = ks*64 + (l>>4)*16 .. +16 (1 byte per k).
__global__ __launch_bounds__(256) void k_prep(
    const float* __restrict__ gp, const float* __restrict__ Wm,
    const float* __restrict__ hs,
    const int* __restrict__ gstart, const int* __restrict__ gend,
    int4v* __restrict__ a_ws, int4v* __restrict__ b_ws,
    float* __restrict__ pp)         // [BB][SEG_SLICES][HH] partial sums
{
    __shared__ __align__(16) float xs[16][LDST];   // 49.4 KB
    const int bid = blockIdx.x;
    const int t = threadIdx.x;

    if (bid < A_RG + B_RG) {
        const bool isA = bid < A_RG;
        const int rg = isA ? bid : (bid - A_RG);
        const float* src = (isA ? gp : Wm) + (size_t)rg * 16 * HH;
        int4v* dst = isA ? a_ws : b_ws;
        const float sc = isA ? SCALE_X : SCALE_W;

        // coalesced stage: 16 rows x 768 floats, contiguous in global
#pragma unroll
        for (int j = 0; j < 12; ++j) {
            const int idx = t + j * 256;        // 0..3071 float4s
            const int row = idx / 192;
            const int col = (idx - row * 192) * 4;
            *(float4*)&xs[row][col] = *(const float4*)(src + (size_t)idx * 4);
        }
        __syncthreads();

        const int l = t & 63;
        const int cslot = t >> 6;               // 0..3
        const int row = l & 15;
        const int koff = (l >> 4) * 16;
#pragma unroll
        for (int i = 0; i < 3; ++i) {
            const int ks = i * 4 + cslot;
            const int kbase = ks * 64 + koff;
            union { signed char c[16]; int4v v; } Hc, Lc;
#pragma unroll
            for (int q = 0; q < 4; ++q) {
                const float4 xv = *(const float4*)&xs[row][kbase + 4 * q];
                quant(xv.x, sc, Hc.c[4 * q + 0], Lc.c[4 * q + 0]);
                quant(xv.y, sc, Hc.c[4 * q + 1], Lc.c[4 * q + 1]);
                quant(xv.z, sc, Hc.c[4 * q + 2], Lc.c[4 * q + 2]);
                quant(xv.w, sc, Hc.c[4 * q + 3], Lc.c[4 * q + 3]);
            }
            dst[(size_t)(rg * NKS + ks) * 128 + l]      = Hc.v;
            dst[(size_t)(rg * NKS + ks) * 128 + 64 + l] = Lc.v;
        }
    } else {
        const int id = bid - (A_RG + B_RG);
        const int b = id >> 3;
        const int sl = id & 7;
        const int s0 = gstart[b], e0 = gend[b];
        const int lo = max(s0, sl * 64);
        const int hi = min(e0, sl * 64 + 64);
        const float* base = hs + (size_t)b * LL * HH;
        const int c0 = t, c1 = t + 256, c2 = t + 512;
        float a[3][4];
#pragma unroll
        for (int j = 0; j < 3; ++j)
#pragma unroll
            for (int u = 0; u < 4; ++u) a[j][u] = 0.f;
        int l = lo;
        for (; l + 4 <= hi; l += 4) {
#pragma unroll
            for (int u = 0; u < 4; ++u) {
                const float* row = base + (size_t)(l + u) * HH;
                a[0][u] += row[c0]; a[1][u] += row[c1]; a[2][u] += row[c2];
            }
        }
        for (; l < hi; ++l) {
            const float* row = base + (size_t)l * HH;
            a[0][0] += row[c0]; a[1][0] += row[c1]; a[2][0] += row[c2];
        }
        float* dst = pp + (size_t)id * HH;
        dst[c0] = (a[0][0] + a[0][1]) + (a[0][2] + a[0][3]);
        dst[c1] = (a[1][0] + a[1][1]) + (a[1][2] + a[1][3]);
        dst[c2] = (a[2][0] + a[2][1]) + (a[2][2] + a[2][3]);
    }
}

// K2: blocks [0,384): t = gp @ W^T via 2-chain int8 MFMA, SPLIT-K 2-wave pairs.
//     4 waves/block: pair p = wave>>1 owns a 32m x 64n tile; kw = wave&1 computes
//     k-half (6 of 12 steps). Integer-exact combine via LDS, each wave epilogues
//     one 16-row group. 1536 waves total (1.5/SIMD).
//     blocks [384,448): combine segmean partials + LN(g2,b2) -> sel, selnorm.
#define TRIO(MI, NI, AH_, AL_, BH_, BL_) \
    accH[MI][NI] = __builtin_amdgcn_mfma_i32_16x16x64_i8(AH_, BH_, accH[MI][NI], 0, 0, 0); \
    accM[MI][NI] = __builtin_amdgcn_mfma_i32_16x16x64_i8(AH_, BL_, accM[MI][NI], 0, 0, 0); \
    accM[MI][NI] = __builtin_amdgcn_mfma_i32_16x16x64_i8(AL_, BH_, accM[MI][NI], 0, 0, 0);

#define DECLSET(P) int4v P##a0h,P##a0l,P##a1h,P##a1l, \
    P##b0h,P##b0l,P##b1h,P##b1l,P##b2h,P##b2l,P##b3h,P##b3l;

#define LOADSET(P, KS) { const int o_ = (KS) * 128; \
    P##a0h = ba0[o_]; P##a0l = ba0[o_ + 64]; P##a1h = ba1[o_]; P##a1l = ba1[o_ + 64]; \
    P##b0h = bb0[o_]; P##b0l = bb0[o_ + 64]; P##b1h = bb1[o_]; P##b1l = bb1[o_ + 64]; \
    P##b2h = bb2[o_]; P##b2l = bb2[o_ + 64]; P##b3h = bb3[o_]; P##b3l = bb3[o_ + 64]; }

#define MFMASET(P) \
    TRIO(0, 0, P##a0h, P##a0l, P##b0h, P##b0l) \
    TRIO(0, 1, P##a0h, P##a0l, P##b1h, P##b1l) \
    TRIO(0, 2, P##a0h, P##a0l, P##b2h, P##b2l) \
    TRIO(0, 3, P##a0h, P##a0l, P##b3h, P##b3l) \
    TRIO(1, 0, P##a1h, P##a1l, P##b0h, P##b0l) \
    TRIO(1, 1, P##a1h, P##a1l, P##b1h, P##b1l) \
    TRIO(1, 2, P##a1h, P##a1l, P##b2h, P##b2l) \
    TRIO(1, 3, P##a1h, P##a1l, P##b3h, P##b3l)

__global__ __launch_bounds__(256) void k_gemm(
    const int4v* __restrict__ aw, const int4v* __restrict__ bw,
    const float* __restrict__ pp,
    const float* __restrict__ g2, const float* __restrict__ b2,
    const int* __restrict__ gstart, const int* __restrict__ gend,
    float* __restrict__ tbuf, float* __restrict__ sel, float* __restrict__ selnorm)
{
    __shared__ int ldsx[2][2][64 * 36];     // 36.9 KB, stride-36 pad (bank-safe)
    __shared__ float red[2][4], red2[4], sh2[2];

    if (blockIdx.x < NGB) {
        const int orig = blockIdx.x;
        const int bid = (orig & 7) * 48 + (orig >> 3);   // XCD swizzle (384 % 8 == 0)
        const int mb = bid / 12;
        const int nb = bid - mb * 12;
        const int wave = threadIdx.x >> 6;
        const int p = wave >> 1;            // pair: which 32m half of the 64m tile
        const int kw = wave & 1;            // k-half
        const int lane = threadIdx.x & 63;

        const int mg0 = mb * 4 + p * 2;
        const int4v* ba0 = aw + (size_t)mg0 * CH_PER_G + lane;
        const int4v* ba1 = ba0 + CH_PER_G;
        const int4v* bb0 = bw + (size_t)(nb * 4) * CH_PER_G + lane;
        const int4v* bb1 = bb0 + CH_PER_G;
        const int4v* bb2 = bb1 + CH_PER_G;
        const int4v* bb3 = bb2 + CH_PER_G;

        int4v accH[2][4] = {};
        int4v accM[2][4] = {};
        DECLSET(A) DECLSET(C)

        const int ko = kw * 6;
        LOADSET(A, ko + 0)
        for (int ks = 0; ks < 4; ks += 2) {
            LOADSET(C, ko + ks + 1)
            MFMASET(A)
            LOADSET(A, ko + ks + 2)
            MFMASET(C)
        }
        LOADSET(C, ko + 5)
        MFMASET(A)
        MFMASET(C)

        // split-K combine: each wave keeps mi==kw, ships mi==1-kw to its partner
        {
            const int mi_w = 1 - kw;
            int4v* slot = (int4v*)&ldsx[p][kw][lane * 36];
#pragma unroll
            for (int ni = 0; ni < 4; ++ni) {
                slot[ni]     = accH[mi_w][ni];
                slot[4 + ni] = accM[mi_w][ni];
            }
        }
        __syncthreads();
        int4v hfin[4], mfin[4];
        {
            const int4v* pslot = (const int4v*)&ldsx[p][1 - kw][lane * 36];
#pragma unroll
            for (int ni = 0; ni < 4; ++ni) {
                hfin[ni] = accH[kw][ni] + pslot[ni];
                mfin[ni] = accM[kw][ni] + pslot[4 + ni];
            }
        }

        // epilogue: this wave writes row-group mg0+kw.
        // C frag: col = lane&15, row = (lane>>4)*4 + j; t = (H*2^16 + M*2^8)*2^-29
        const int wm = (mg0 + kw) * 16;
        const int wn = nb * 64;
        const int r0 = (lane >> 4) * 4;
        const int cc = lane & 15;
#pragma unroll
        for (int ni = 0; ni < 4; ++ni)
#pragma unroll
            for (int j = 0; j < 4; ++j) {
                const float tv = ((float)hfin[ni][j] * 65536.0f
                                + (float)mfin[ni][j] * 256.0f) * INV_SC;
                tbuf[(size_t)(wm + r0 + j) * HH + wn + ni * 16 + cc] = tv;
            }
    } else {
        // -------- combine segmean partials + LN(g2,b2), 256 threads --------
        const int cb = blockIdx.x - NGB;
        const int t = threadIdx.x;
        const int lane = t & 63, wv = t >> 6;
        const int s0 = gstart[cb], e0 = gend[cb];
        const float inv = 1.0f / fmaxf((float)(e0 - s0), 1.0f);

        float v[3];
#pragma unroll
        for (int j = 0; j < 3; ++j) v[j] = 0.f;
        const float* base = pp + (size_t)cb * SEG_SLICES * HH;
#pragma unroll
        for (int sl = 0; sl < SEG_SLICES; ++sl) {
#pragma unroll
            for (int j = 0; j < 3; ++j)
                v[j] += base[(size_t)sl * HH + t + 256 * j];
        }
        float s = 0.f, q = 0.f;
#pragma unroll
        for (int j = 0; j < 3; ++j) {
            v[j] *= inv;
            s += v[j];
            q = fmaf(v[j], v[j], q);
        }
        for (int o = 32; o > 0; o >>= 1) {
            s += __shfl_xor(s, o, 64);
            q += __shfl_xor(q, o, 64);
        }
        if (lane == 0) { red[0][wv] = s; red[1][wv] = q; }
        __syncthreads();
        if (t == 0) {
            const float ts = red[0][0] + red[0][1] + red[0][2] + red[0][3];
            const float tq = red[1][0] + red[1][1] + red[1][2] + red[1][3];
            const float mu = ts / (float)HH;
            const float var = tq / (float)HH - mu * mu;
            sh2[0] = mu;
            sh2[1] = rsqrtf(var + EPS_LN);
        }
        __syncthreads();
        const float mu = sh2[0], rinv = sh2[1];
        float n = 0.f;
#pragma unroll
        for (int j = 0; j < 3; ++j) {
            const int c = t + 256 * j;
            const float y = (v[j] - mu) * rinv * g2[c] + b2[c];
            sel[(size_t)cb * HH + c] = y;
            n = fmaf(y, y, n);
        }
        for (int o = 32; o > 0; o >>= 1) n += __shfl_xor(n, o, 64);
        if (lane == 0) red2[wv] = n;
        __syncthreads();
        if (t == 0) selnorm[cb] = sqrtf(red2[0] + red2[1] + red2[2] + red2[3]);
    }
}

// K3: per-row LN(g1,b1) + cosine vs sel. One wave per t-row, float4 loads.
__global__ __launch_bounds__(512) void k_finish(
    const float* __restrict__ tbuf, const float* __restrict__ bias,
    const float* __restrict__ g1, const float* __restrict__ b1,
    const float* __restrict__ sel, const float* __restrict__ selnorm,
    float* __restrict__ out)
{
    const int lane = threadIdx.x & 63;
    const int w = threadIdx.x >> 6;
    const int m = blockIdx.x * 8 + w;
    const int b = m >> 5;
    const float4* t4  = (const float4*)(tbuf + (size_t)m * HH);
    const float4* bi4 = (const float4*)bias;
    const float4* g14 = (const float4*)g1;
    const float4* b14 = (const float4*)b1;
    const float4* s4  = (const float4*)(sel + (size_t)b * HH);

    float4 v4[3];
    float s = 0.f, q = 0.f;
#pragma unroll
    for (int j = 0; j < 3; ++j) {
        const int idx = lane + 64 * j;
        const float4 a = t4[idx];
        const float4 bb = bi4[idx];
        v4[j].x = a.x + bb.x; v4[j].y = a.y + bb.y;
        v4[j].z = a.z + bb.z; v4[j].w = a.w + bb.w;
        s += (v4[j].x + v4[j].y) + (v4[j].z + v4[j].w);
        q = fmaf(v4[j].x, v4[j].x, q); q = fmaf(v4[j].y, v4[j].y, q);
        q = fmaf(v4[j].z, v4[j].z, q); q = fmaf(v4[j].w, v4[j].w, q);
    }
    for (int o = 32; o > 0; o >>= 1) {
        s += __shfl_xor(s, o, 64);
        q += __shfl_xor(q, o, 64);
    }
    const float mu = s * (1.0f / (float)HH);
    const float var = q * (1.0f / (float)HH) - mu * mu;
    const float rinv = rsqrtf(var + EPS_LN);

    float d = 0.f, n2 = 0.f;
#pragma unroll
    for (int j = 0; j < 3; ++j) {
        const int idx = lane + 64 * j;
        const float4 g = g14[idx];
        const float4 be = b14[idx];
        const float4 se = s4[idx];
        float y;
        y = (v4[j].x - mu) * rinv * g.x + be.x; d = fmaf(y, se.x, d); n2 = fmaf(y, y, n2);
        y = (v4[j].y - mu) * rinv * g.y + be.y; d = fmaf(y, se.y, d); n2 = fmaf(y, y, n2);
        y = (v4[j].z - mu) * rinv * g.z + be.z; d = fmaf(y, se.z, d); n2 = fmaf(y, y, n2);
        y = (v4[j].w - mu) * rinv * g.w + be.w; d = fmaf(y, se.w, d); n2 = fmaf(y, y, n2);
    }
    for (int o = 32; o > 0; o >>= 1) {
        d += __shfl_xor(d, o, 64);
        n2 += __shfl_xor(n2, o, 64);
    }
    if (lane == 0)
        out[m] = d / fmaxf(selnorm[b] * sqrtf(n2), EPS_COS);
}

extern "C" void kernel_launch(void* const* d_in, const int* in_sizes, int n_in,
                              void* d_out, int out_size, void* d_ws, size_t ws_size,
                              hipStream_t stream) {
    const float* hs  = (const float*)d_in[0];
    const float* gp  = (const float*)d_in[1];
    const float* W   = (const float*)d_in[2];
    const float* bia = (const float*)d_in[3];
    const float* g1  = (const float*)d_in[4];
    const float* b1  = (const float*)d_in[5];
    const float* g2  = (const float*)d_in[6];
    const float* b2  = (const float*)d_in[7];
    const int* gs    = (const int*)d_in[8];
    const int* ge    = (const int*)d_in[9];
    float* out = (float*)d_out;

    char* ws = (char*)d_ws;
    int4v* a_ws  = (int4v*)ws;                                          // 3.15 MB
    int4v* b_ws  = (int4v*)(ws + (size_t)A_RG * CH_PER_G * 16);         // 1.18 MB
    float* pp      = (float*)(ws + (size_t)(A_RG + B_RG) * CH_PER_G * 16); // 1.57 MB
    float* sel     = pp + (size_t)BB * SEG_SLICES * HH;                 // 196 KB
    float* selnorm = sel + (size_t)BB * HH;
    float* tbuf    = selnorm + BB;                                      // 6.29 MB

    k_prep<<<A_RG + B_RG + SEG_BLK, 256, 0, stream>>>(gp, W, hs, gs, ge,
                                                      a_ws, b_ws, pp);
    k_gemm<<<NGB + BB, 256, 0, stream>>>(a_ws, b_ws, pp, g2, b2, gs, ge,
                                         tbuf, sel, selnorm);
    k_finish<<<MM / 8, 512, 0, stream>>>(tbuf, bia, g1, b1, sel, selnorm, out);
}

// Round 11
// 28.044 us; speedup vs baseline: 1.3361x; 1.3361x over previous
//
#include <hip/hip_runtime.h>
#include <hip/hip_bf16.h>
#include <math.h>

#define BB 64
#define LL 512
#define HH 768
#define SS 32
#define MM 2048
#define EPS_LN 1e-12f
#define EPS_COS 1e-8f

#define NKS 12                  // k-steps of 64 (i8 MFMA)
#define NGB 384                 // gemm blocks (64m x 64n tiles: 32 x 12)
#define CH_PER_G (NKS * 2 * 64) // int4v chunks per row-group: 1536
#define A_RG (MM / 16)          // 128
#define B_RG (HH / 16)          // 48
#define LDST 772                // LDS row stride (floats)
#define SEG_SLICES 8
#define SEG_BLK (BB * SEG_SLICES)   // 512

#define SCALE_X 4096.0f         // 2^12
#define SCALE_W 131072.0f       // 2^17
#define INV_SC  1.8626451e-9f   // 2^-29

typedef __attribute__((ext_vector_type(4))) int int4v;

static __device__ inline void quant(float x, float scale,
                                    signed char& hi, signed char& lo) {
    int v = (int)rintf(x * scale);
    v = max(-32639, min(32639, v));
    const signed char l8 = (signed char)(v & 0xFF);
    hi = (signed char)((v - (int)l8) >> 8);
    lo = l8;
}

// K1: bid [0,512): segmean partial sums (slice sl of batch b, early dispatch);
//     bid [512,640): quant-split gp row-group; [640,688): quant-split W.
// Chunk layout (int4v units): rg*1536 + ks*128 + plane*64 + lane; lane l holds
// row rg*16+(l&15), k = ks*64 + (l>>4)*16 .. +16 (1 byte per k).
__global__ __launch_bounds__(256) void k_prep(
    const float* __restrict__ gp, const float* __restrict__ Wm,
    const float* __restrict__ hs,
    const int* __restrict__ gstart, const int* __restrict__ gend,
    int4v* __restrict__ a_ws, int4v* __restrict__ b_ws,
    float* __restrict__ pp)         // [BB][SEG_SLICES][HH] partial sums
{
    __shared__ __align__(16) float xs[16][LDST];   // 49.4 KB
    const int bid = blockIdx.x;
    const int t = threadIdx.x;

    if (bid < SEG_BLK) {
        const int b = bid >> 3;
        const int sl = bid & 7;
        const int s0 = gstart[b], e0 = gend[b];
        const int lo = max(s0, sl * 64);
        const int hi = min(e0, sl * 64 + 64);
        const float* base = hs + (size_t)b * LL * HH;
        const int c0 = t, c1 = t + 256, c2 = t + 512;
        float a[3][4];
#pragma unroll
        for (int j = 0; j < 3; ++j)
#pragma unroll
            for (int u = 0; u < 4; ++u) a[j][u] = 0.f;
        int l = lo;
        for (; l + 4 <= hi; l += 4) {
#pragma unroll
            for (int u = 0; u < 4; ++u) {
                const float* row = base + (size_t)(l + u) * HH;
                a[0][u] += row[c0]; a[1][u] += row[c1]; a[2][u] += row[c2];
            }
        }
        for (; l < hi; ++l) {
            const float* row = base + (size_t)l * HH;
            a[0][0] += row[c0]; a[1][0] += row[c1]; a[2][0] += row[c2];
        }
        float* dst = pp + (size_t)bid * HH;
        dst[c0] = (a[0][0] + a[0][1]) + (a[0][2] + a[0][3]);
        dst[c1] = (a[1][0] + a[1][1]) + (a[1][2] + a[1][3]);
        dst[c2] = (a[2][0] + a[2][1]) + (a[2][2] + a[2][3]);
    } else {
        const bool isA = bid < SEG_BLK + A_RG;
        const int rg = isA ? (bid - SEG_BLK) : (bid - SEG_BLK - A_RG);
        const float* src = (isA ? gp : Wm) + (size_t)rg * 16 * HH;
        int4v* dst = isA ? a_ws : b_ws;
        const float sc = isA ? SCALE_X : SCALE_W;

        // coalesced stage: 16 rows x 768 floats, contiguous in global
#pragma unroll
        for (int j = 0; j < 12; ++j) {
            const int idx = t + j * 256;        // 0..3071 float4s
            const int row = idx / 192;
            const int col = (idx - row * 192) * 4;
            *(float4*)&xs[row][col] = *(const float4*)(src + (size_t)idx * 4);
        }
        __syncthreads();

        const int l = t & 63;
        const int cslot = t >> 6;               // 0..3
        const int row = l & 15;
        const int koff = (l >> 4) * 16;
#pragma unroll
        for (int i = 0; i < 3; ++i) {
            const int ks = i * 4 + cslot;
            const int kbase = ks * 64 + koff;
            union { signed char c[16]; int4v v; } Hc, Lc;
#pragma unroll
            for (int q = 0; q < 4; ++q) {
                const float4 xv = *(const float4*)&xs[row][kbase + 4 * q];
                quant(xv.x, sc, Hc.c[4 * q + 0], Lc.c[4 * q + 0]);
                quant(xv.y, sc, Hc.c[4 * q + 1], Lc.c[4 * q + 1]);
                quant(xv.z, sc, Hc.c[4 * q + 2], Lc.c[4 * q + 2]);
                quant(xv.w, sc, Hc.c[4 * q + 3], Lc.c[4 * q + 3]);
            }
            dst[(size_t)(rg * NKS + ks) * 128 + l]      = Hc.v;
            dst[(size_t)(rg * NKS + ks) * 128 + 64 + l] = Lc.v;
        }
    }
}

// K2: blocks [0,384): t = gp @ W^T via 2-chain int8 MFMA (no LDS, no barriers).
//     blocks [384,448): combine segmean partials + LN(g2,b2) -> sel, selnorm.
#define TRIO(MI, NI, AH_, AL_, BH_, BL_) \
    accH[MI][NI] = __builtin_amdgcn_mfma_i32_16x16x64_i8(AH_, BH_, accH[MI][NI], 0, 0, 0); \
    accM[MI][NI] = __builtin_amdgcn_mfma_i32_16x16x64_i8(AH_, BL_, accM[MI][NI], 0, 0, 0); \
    accM[MI][NI] = __builtin_amdgcn_mfma_i32_16x16x64_i8(AL_, BH_, accM[MI][NI], 0, 0, 0);

#define DECLSET(P) int4v P##a0h,P##a0l,P##a1h,P##a1l, \
    P##b0h,P##b0l,P##b1h,P##b1l,P##b2h,P##b2l,P##b3h,P##b3l;

#define LOADSET(P, KS) { const int o_ = (KS) * 128; \
    P##a0h = ba0[o_]; P##a0l = ba0[o_ + 64]; P##a1h = ba1[o_]; P##a1l = ba1[o_ + 64]; \
    P##b0h = bb0[o_]; P##b0l = bb0[o_ + 64]; P##b1h = bb1[o_]; P##b1l = bb1[o_ + 64]; \
    P##b2h = bb2[o_]; P##b2l = bb2[o_ + 64]; P##b3h = bb3[o_]; P##b3l = bb3[o_ + 64]; }

#define MFMASET(P) \
    TRIO(0, 0, P##a0h, P##a0l, P##b0h, P##b0l) \
    TRIO(0, 1, P##a0h, P##a0l, P##b1h, P##b1l) \
    TRIO(0, 2, P##a0h, P##a0l, P##b2h, P##b2l) \
    TRIO(0, 3, P##a0h, P##a0l, P##b3h, P##b3l) \
    TRIO(1, 0, P##a1h, P##a1l, P##b0h, P##b0l) \
    TRIO(1, 1, P##a1h, P##a1l, P##b1h, P##b1l) \
    TRIO(1, 2, P##a1h, P##a1l, P##b2h, P##b2l) \
    TRIO(1, 3, P##a1h, P##a1l, P##b3h, P##b3l)

__global__ __launch_bounds__(128) void k_gemm(
    const int4v* __restrict__ aw, const int4v* __restrict__ bw,
    const float* __restrict__ pp,
    const float* __restrict__ g2, const float* __restrict__ b2,
    const int* __restrict__ gstart, const int* __restrict__ gend,
    float* __restrict__ tbuf, float* __restrict__ sel, float* __restrict__ selnorm)
{
    __shared__ float red[2][2], red2[2], sh2[2];

    if (blockIdx.x < NGB) {
        const int orig = blockIdx.x;
        const int bid = (orig & 7) * 48 + (orig >> 3);   // XCD swizzle (384 % 8 == 0)
        const int mb = bid / 12;
        const int nb = bid - mb * 12;
        const int wave = threadIdx.x >> 6;
        const int lane = threadIdx.x & 63;

        const int mg0 = mb * 4 + wave * 2;
        const int4v* ba0 = aw + (size_t)mg0 * CH_PER_G + lane;
        const int4v* ba1 = ba0 + CH_PER_G;
        const int4v* bb0 = bw + (size_t)(nb * 4) * CH_PER_G + lane;
        const int4v* bb1 = bb0 + CH_PER_G;
        const int4v* bb2 = bb1 + CH_PER_G;
        const int4v* bb3 = bb2 + CH_PER_G;

        int4v accH[2][4] = {};
        int4v accM[2][4] = {};
        DECLSET(A) DECLSET(C)

        LOADSET(A, 0)
        for (int ks = 0; ks < NKS - 2; ks += 2) {
            LOADSET(C, ks + 1)
            MFMASET(A)
            LOADSET(A, ks + 2)
            MFMASET(C)
        }
        LOADSET(C, NKS - 1)
        MFMASET(A)
        MFMASET(C)

        // C frag: col = lane&15, row = (lane>>4)*4 + j; t = (HH*2^16 + M*2^8)*2^-29
        const int wm = mg0 * 16;
        const int wn = nb * 64;
        const int r0 = (lane >> 4) * 4;
        const int cc = lane & 15;
#pragma unroll
        for (int mi = 0; mi < 2; ++mi)
#pragma unroll
            for (int ni = 0; ni < 4; ++ni)
#pragma unroll
                for (int j = 0; j < 4; ++j) {
                    const float tv = ((float)accH[mi][ni][j] * 65536.0f
                                    + (float)accM[mi][ni][j] * 256.0f) * INV_SC;
                    tbuf[(size_t)(wm + mi * 16 + r0 + j) * HH + wn + ni * 16 + cc] = tv;
                }
    } else {
        // -------- combine segmean partials + LN(g2,b2) --------
        const int cb = blockIdx.x - NGB;
        const int t = threadIdx.x;
        const int lane = t & 63, wv = t >> 6;
        const int s0 = gstart[cb], e0 = gend[cb];
        const float inv = 1.0f / fmaxf((float)(e0 - s0), 1.0f);

        float v[6];
#pragma unroll
        for (int j = 0; j < 6; ++j) v[j] = 0.f;
        const float* base = pp + (size_t)cb * SEG_SLICES * HH;
#pragma unroll
        for (int sl = 0; sl < SEG_SLICES; ++sl) {
#pragma unroll
            for (int j = 0; j < 6; ++j)
                v[j] += base[(size_t)sl * HH + t + 128 * j];
        }
        float s = 0.f, q = 0.f;
#pragma unroll
        for (int j = 0; j < 6; ++j) {
            v[j] *= inv;
            s += v[j];
            q = fmaf(v[j], v[j], q);
        }
        for (int o = 32; o > 0; o >>= 1) {
            s += __shfl_xor(s, o, 64);
            q += __shfl_xor(q, o, 64);
        }
        if (lane == 0) { red[0][wv] = s; red[1][wv] = q; }
        __syncthreads();
        if (t == 0) {
            const float ts = red[0][0] + red[0][1];
            const float tq = red[1][0] + red[1][1];
            const float mu = ts / (float)HH;
            const float var = tq / (float)HH - mu * mu;
            sh2[0] = mu;
            sh2[1] = rsqrtf(var + EPS_LN);
        }
        __syncthreads();
        const float mu = sh2[0], rinv = sh2[1];
        float n = 0.f;
#pragma unroll
        for (int j = 0; j < 6; ++j) {
            const int c = t + 128 * j;
            const float y = (v[j] - mu) * rinv * g2[c] + b2[c];
            sel[(size_t)cb * HH + c] = y;
            n = fmaf(y, y, n);
        }
        for (int o = 32; o > 0; o >>= 1) n += __shfl_xor(n, o, 64);
        if (lane == 0) red2[wv] = n;
        __syncthreads();
        if (t == 0) selnorm[cb] = sqrtf(red2[0] + red2[1]);
    }
}

// K3: per-row LN(g1,b1) + cosine vs sel. One wave per t-row, float4 loads.
__global__ __launch_bounds__(512) void k_finish(
    const float* __restrict__ tbuf, const float* __restrict__ bias,
    const float* __restrict__ g1, const float* __restrict__ b1,
    const float* __restrict__ sel, const float* __restrict__ selnorm,
    float* __restrict__ out)
{
    const int lane = threadIdx.x & 63;
    const int w = threadIdx.x >> 6;
    const int m = blockIdx.x * 8 + w;
    const int b = m >> 5;
    const float4* t4  = (const float4*)(tbuf + (size_t)m * HH);
    const float4* bi4 = (const float4*)bias;
    const float4* g14 = (const float4*)g1;
    const float4* b14 = (const float4*)b1;
    const float4* s4  = (const float4*)(sel + (size_t)b * HH);

    float4 v4[3];
    float s = 0.f, q = 0.f;
#pragma unroll
    for (int j = 0; j < 3; ++j) {
        const int idx = lane + 64 * j;
        const float4 a = t4[idx];
        const float4 bb = bi4[idx];
        v4[j].x = a.x + bb.x; v4[j].y = a.y + bb.y;
        v4[j].z = a.z + bb.z; v4[j].w = a.w + bb.w;
        s += (v4[j].x + v4[j].y) + (v4[j].z + v4[j].w);
        q = fmaf(v4[j].x, v4[j].x, q); q = fmaf(v4[j].y, v4[j].y, q);
        q = fmaf(v4[j].z, v4[j].z, q); q = fmaf(v4[j].w, v4[j].w, q);
    }
    for (int o = 32; o > 0; o >>= 1) {
        s += __shfl_xor(s, o, 64);
        q += __shfl_xor(q, o, 64);
    }
    const float mu = s * (1.0f / (float)HH);
    const float var = q * (1.0f / (float)HH) - mu * mu;
    const float rinv = rsqrtf(var + EPS_LN);

    float d = 0.f, n2 = 0.f;
#pragma unroll
    for (int j = 0; j < 3; ++j) {
        const int idx = lane + 64 * j;
        const float4 g = g14[idx];
        const float4 be = b14[idx];
        const float4 se = s4[idx];
        float y;
        y = (v4[j].x - mu) * rinv * g.x + be.x; d = fmaf(y, se.x, d); n2 = fmaf(y, y, n2);
        y = (v4[j].y - mu) * rinv * g.y + be.y; d = fmaf(y, se.y, d); n2 = fmaf(y, y, n2);
        y = (v4[j].z - mu) * rinv * g.z + be.z; d = fmaf(y, se.z, d); n2 = fmaf(y, y, n2);
        y = (v4[j].w - mu) * rinv * g.w + be.w; d = fmaf(y, se.w, d); n2 = fmaf(y, y, n2);
    }
    for (int o = 32; o > 0; o >>= 1) {
        d += __shfl_xor(d, o, 64);
        n2 += __shfl_xor(n2, o, 64);
    }
    if (lane == 0)
        out[m] = d / fmaxf(selnorm[b] * sqrtf(n2), EPS_COS);
}

extern "C" void kernel_launch(void* const* d_in, const int* in_sizes, int n_in,
                              void* d_out, int out_size, void* d_ws, size_t ws_size,
                              hipStream_t stream) {
    const float* hs  = (const float*)d_in[0];
    const float* gp  = (const float*)d_in[1];
    const float* W   = (const float*)d_in[2];
    const float* bia = (const float*)d_in[3];
    const float* g1  = (const float*)d_in[4];
    const float* b1  = (const float*)d_in[5];
    const float* g2  = (const float*)d_in[6];
    const float* b2  = (const float*)d_in[7];
    const int* gs    = (const int*)d_in[8];
    const int* ge    = (const int*)d_in[9];
    float* out = (float*)d_out;

    char* ws = (char*)d_ws;
    int4v* a_ws  = (int4v*)ws;                                          // 3.15 MB
    int4v* b_ws  = (int4v*)(ws + (size_t)A_RG * CH_PER_G * 16);         // 1.18 MB
    float* pp      = (float*)(ws + (size_t)(A_RG + B_RG) * CH_PER_G * 16); // 1.57 MB
    float* sel     = pp + (size_t)BB * SEG_SLICES * HH;                 // 196 KB
    float* selnorm = sel + (size_t)BB * HH;
    float* tbuf    = selnorm + BB;                                      // 6.29 MB

    k_prep<<<SEG_BLK + A_RG + B_RG, 256, 0, stream>>>(gp, W, hs, gs, ge,
                                                      a_ws, b_ws, pp);
    k_gemm<<<NGB + BB, 128, 0, stream>>>(a_ws, b_ws, pp, g2, b2, gs, ge,
                                         tbuf, sel, selnorm);
    k_finish<<<MM / 8, 512, 0, stream>>>(tbuf, bia, g1, b1, sel, selnorm, out);
}

// Round 12
// 27.183 us; speedup vs baseline: 1.3785x; 1.0317x over previous
//
#include <hip/hip_runtime.h>
#include <hip/hip_bf16.h>
#include <math.h>

#define BB 64
#define LL 512
#define HH 768
#define SS 32
#define MM 2048
#define EPS_LN 1e-12f
#define EPS_COS 1e-8f

#define NKS 12                  // k-steps of 64 (i8 MFMA)
#define NGB 384                 // gemm blocks (64m x 64n tiles: 32 x 12)
#define CH_PER_G (NKS * 2 * 64) // int4v chunks per row-group: 1536
#define A_RG (MM / 16)          // 128
#define B_RG (HH / 16)          // 48
#define LDST 772                // LDS row stride (floats)
#define SEG_SLICES 8
#define SEG_BLK (BB * SEG_SLICES)   // 512

#define SCALE_X 4096.0f         // 2^12
#define SCALE_W 131072.0f       // 2^17
#define INV_SC  1.8626451e-9f   // 2^-29

typedef __attribute__((ext_vector_type(4))) int int4v;

static __device__ inline void quant(float x, float scale,
                                    signed char& hi, signed char& lo) {
    int v = (int)rintf(x * scale);
    v = max(-32639, min(32639, v));
    const signed char l8 = (signed char)(v & 0xFF);
    hi = (signed char)((v - (int)l8) >> 8);
    lo = l8;
}

static __device__ inline unsigned short f2bfu(float x) {
    __hip_bfloat16 h = __float2bfloat16(x);
    unsigned short b; __builtin_memcpy(&b, &h, 2); return b;
}
static __device__ inline float bf2f(unsigned short b) {
    __hip_bfloat16 h; __builtin_memcpy(&h, &b, 2); return __bfloat162float(h);
}

// K1: bid [0,512): segmean partial sums (slice sl of batch b, early dispatch);
//     bid [512,640): quant-split gp row-group; [640,688): quant-split W.
// Chunk layout (int4v units): rg*1536 + ks*128 + plane*64 + lane; lane l holds
// row rg*16+(l&15), k = ks*64 + (l>>4)*16 .. +16 (1 byte per k).
__global__ __launch_bounds__(256) void k_prep(
    const float* __restrict__ gp, const float* __restrict__ Wm,
    const float* __restrict__ hs,
    const int* __restrict__ gstart, const int* __restrict__ gend,
    int4v* __restrict__ a_ws, int4v* __restrict__ b_ws,
    float* __restrict__ pp)         // [BB][SEG_SLICES][HH] partial sums
{
    __shared__ __align__(16) float xs[16][LDST];   // 49.4 KB
    const int bid = blockIdx.x;
    const int t = threadIdx.x;

    if (bid < SEG_BLK) {
        const int b = bid >> 3;
        const int sl = bid & 7;
        const int s0 = gstart[b], e0 = gend[b];
        const int lo = max(s0, sl * 64);
        const int hi = min(e0, sl * 64 + 64);
        const float* base = hs + (size_t)b * LL * HH;
        const int c0 = t, c1 = t + 256, c2 = t + 512;
        float a[3][4];
#pragma unroll
        for (int j = 0; j < 3; ++j)
#pragma unroll
            for (int u = 0; u < 4; ++u) a[j][u] = 0.f;
        int l = lo;
        for (; l + 4 <= hi; l += 4) {
#pragma unroll
            for (int u = 0; u < 4; ++u) {
                const float* row = base + (size_t)(l + u) * HH;
                a[0][u] += row[c0]; a[1][u] += row[c1]; a[2][u] += row[c2];
            }
        }
        for (; l < hi; ++l) {
            const float* row = base + (size_t)l * HH;
            a[0][0] += row[c0]; a[1][0] += row[c1]; a[2][0] += row[c2];
        }
        float* dst = pp + (size_t)bid * HH;
        dst[c0] = (a[0][0] + a[0][1]) + (a[0][2] + a[0][3]);
        dst[c1] = (a[1][0] + a[1][1]) + (a[1][2] + a[1][3]);
        dst[c2] = (a[2][0] + a[2][1]) + (a[2][2] + a[2][3]);
    } else {
        const bool isA = bid < SEG_BLK + A_RG;
        const int rg = isA ? (bid - SEG_BLK) : (bid - SEG_BLK - A_RG);
        const float* src = (isA ? gp : Wm) + (size_t)rg * 16 * HH;
        int4v* dst = isA ? a_ws : b_ws;
        const float sc = isA ? SCALE_X : SCALE_W;

        // coalesced stage: 16 rows x 768 floats, contiguous in global
#pragma unroll
        for (int j = 0; j < 12; ++j) {
            const int idx = t + j * 256;        // 0..3071 float4s
            const int row = idx / 192;
            const int col = (idx - row * 192) * 4;
            *(float4*)&xs[row][col] = *(const float4*)(src + (size_t)idx * 4);
        }
        __syncthreads();

        const int l = t & 63;
        const int cslot = t >> 6;               // 0..3
        const int row = l & 15;
        const int koff = (l >> 4) * 16;
#pragma unroll
        for (int i = 0; i < 3; ++i) {
            const int ks = i * 4 + cslot;
            const int kbase = ks * 64 + koff;
            union { signed char c[16]; int4v v; } Hc, Lc;
#pragma unroll
            for (int q = 0; q < 4; ++q) {
                const float4 xv = *(const float4*)&xs[row][kbase + 4 * q];
                quant(xv.x, sc, Hc.c[4 * q + 0], Lc.c[4 * q + 0]);
                quant(xv.y, sc, Hc.c[4 * q + 1], Lc.c[4 * q + 1]);
                quant(xv.z, sc, Hc.c[4 * q + 2], Lc.c[4 * q + 2]);
                quant(xv.w, sc, Hc.c[4 * q + 3], Lc.c[4 * q + 3]);
            }
            dst[(size_t)(rg * NKS + ks) * 128 + l]      = Hc.v;
            dst[(size_t)(rg * NKS + ks) * 128 + 64 + l] = Lc.v;
        }
    }
}

// K2: blocks [0,384): t = gp @ W^T via 2-chain int8 MFMA (no LDS, no barriers).
//     tbuf stored as bf16 with bias folded in (halves the t round-trip traffic).
//     blocks [384,448): combine segmean partials + LN(g2,b2) -> sel, selnorm.
#define TRIO(MI, NI, AH_, AL_, BH_, BL_) \
    accH[MI][NI] = __builtin_amdgcn_mfma_i32_16x16x64_i8(AH_, BH_, accH[MI][NI], 0, 0, 0); \
    accM[MI][NI] = __builtin_amdgcn_mfma_i32_16x16x64_i8(AH_, BL_, accM[MI][NI], 0, 0, 0); \
    accM[MI][NI] = __builtin_amdgcn_mfma_i32_16x16x64_i8(AL_, BH_, accM[MI][NI], 0, 0, 0);

#define DECLSET(P) int4v P##a0h,P##a0l,P##a1h,P##a1l, \
    P##b0h,P##b0l,P##b1h,P##b1l,P##b2h,P##b2l,P##b3h,P##b3l;

#define LOADSET(P, KS) { const int o_ = (KS) * 128; \
    P##a0h = ba0[o_]; P##a0l = ba0[o_ + 64]; P##a1h = ba1[o_]; P##a1l = ba1[o_ + 64]; \
    P##b0h = bb0[o_]; P##b0l = bb0[o_ + 64]; P##b1h = bb1[o_]; P##b1l = bb1[o_ + 64]; \
    P##b2h = bb2[o_]; P##b2l = bb2[o_ + 64]; P##b3h = bb3[o_]; P##b3l = bb3[o_ + 64]; }

#define MFMASET(P) \
    TRIO(0, 0, P##a0h, P##a0l, P##b0h, P##b0l) \
    TRIO(0, 1, P##a0h, P##a0l, P##b1h, P##b1l) \
    TRIO(0, 2, P##a0h, P##a0l, P##b2h, P##b2l) \
    TRIO(0, 3, P##a0h, P##a0l, P##b3h, P##b3l) \
    TRIO(1, 0, P##a1h, P##a1l, P##b0h, P##b0l) \
    TRIO(1, 1, P##a1h, P##a1l, P##b1h, P##b1l) \
    TRIO(1, 2, P##a1h, P##a1l, P##b2h, P##b2l) \
    TRIO(1, 3, P##a1h, P##a1l, P##b3h, P##b3l)

__global__ __launch_bounds__(128) void k_gemm(
    const int4v* __restrict__ aw, const int4v* __restrict__ bw,
    const float* __restrict__ bias,
    const float* __restrict__ pp,
    const float* __restrict__ g2, const float* __restrict__ b2,
    const int* __restrict__ gstart, const int* __restrict__ gend,
    unsigned short* __restrict__ tbuf,   // [MM][HH] bf16, bias folded
    float* __restrict__ sel, float* __restrict__ selnorm)
{
    __shared__ float red[2][2], red2[2], sh2[2];

    if (blockIdx.x < NGB) {
        const int orig = blockIdx.x;
        const int bid = (orig & 7) * 48 + (orig >> 3);   // XCD swizzle (384 % 8 == 0)
        const int mb = bid / 12;
        const int nb = bid - mb * 12;
        const int wave = threadIdx.x >> 6;
        const int lane = threadIdx.x & 63;

        const int mg0 = mb * 4 + wave * 2;
        const int4v* ba0 = aw + (size_t)mg0 * CH_PER_G + lane;
        const int4v* ba1 = ba0 + CH_PER_G;
        const int4v* bb0 = bw + (size_t)(nb * 4) * CH_PER_G + lane;
        const int4v* bb1 = bb0 + CH_PER_G;
        const int4v* bb2 = bb1 + CH_PER_G;
        const int4v* bb3 = bb2 + CH_PER_G;

        int4v accH[2][4] = {};
        int4v accM[2][4] = {};
        DECLSET(A) DECLSET(C)

        LOADSET(A, 0)
        for (int ks = 0; ks < NKS - 2; ks += 2) {
            LOADSET(C, ks + 1)
            MFMASET(A)
            LOADSET(A, ks + 2)
            MFMASET(C)
        }
        LOADSET(C, NKS - 1)
        MFMASET(A)
        MFMASET(C)

        // C frag: col = lane&15, row = (lane>>4)*4 + j; t = (H*2^16 + M*2^8)*2^-29 + bias
        const int wm = mg0 * 16;
        const int wn = nb * 64;
        const int r0 = (lane >> 4) * 4;
        const int cc = lane & 15;
        float bias_c[4];
#pragma unroll
        for (int ni = 0; ni < 4; ++ni) bias_c[ni] = bias[wn + ni * 16 + cc];
#pragma unroll
        for (int mi = 0; mi < 2; ++mi)
#pragma unroll
            for (int ni = 0; ni < 4; ++ni)
#pragma unroll
                for (int j = 0; j < 4; ++j) {
                    const float tv = ((float)accH[mi][ni][j] * 65536.0f
                                    + (float)accM[mi][ni][j] * 256.0f) * INV_SC
                                    + bias_c[ni];
                    tbuf[(size_t)(wm + mi * 16 + r0 + j) * HH + wn + ni * 16 + cc] =
                        f2bfu(tv);
                }
    } else {
        // -------- combine segmean partials + LN(g2,b2) --------
        const int cb = blockIdx.x - NGB;
        const int t = threadIdx.x;
        const int lane = t & 63, wv = t >> 6;
        const int s0 = gstart[cb], e0 = gend[cb];
        const float inv = 1.0f / fmaxf((float)(e0 - s0), 1.0f);

        float v[6];
#pragma unroll
        for (int j = 0; j < 6; ++j) v[j] = 0.f;
        const float* base = pp + (size_t)cb * SEG_SLICES * HH;
#pragma unroll
        for (int sl = 0; sl < SEG_SLICES; ++sl) {
#pragma unroll
            for (int j = 0; j < 6; ++j)
                v[j] += base[(size_t)sl * HH + t + 128 * j];
        }
        float s = 0.f, q = 0.f;
#pragma unroll
        for (int j = 0; j < 6; ++j) {
            v[j] *= inv;
            s += v[j];
            q = fmaf(v[j], v[j], q);
        }
        for (int o = 32; o > 0; o >>= 1) {
            s += __shfl_xor(s, o, 64);
            q += __shfl_xor(q, o, 64);
        }
        if (lane == 0) { red[0][wv] = s; red[1][wv] = q; }
        __syncthreads();
        if (t == 0) {
            const float ts = red[0][0] + red[0][1];
            const float tq = red[1][0] + red[1][1];
            const float mu = ts / (float)HH;
            const float var = tq / (float)HH - mu * mu;
            sh2[0] = mu;
            sh2[1] = rsqrtf(var + EPS_LN);
        }
        __syncthreads();
        const float mu = sh2[0], rinv = sh2[1];
        float n = 0.f;
#pragma unroll
        for (int j = 0; j < 6; ++j) {
            const int c = t + 128 * j;
            const float y = (v[j] - mu) * rinv * g2[c] + b2[c];
            sel[(size_t)cb * HH + c] = y;
            n = fmaf(y, y, n);
        }
        for (int o = 32; o > 0; o >>= 1) n += __shfl_xor(n, o, 64);
        if (lane == 0) red2[wv] = n;
        __syncthreads();
        if (t == 0) selnorm[cb] = sqrtf(red2[0] + red2[1]);
    }
}

// K3: per-row LN(g1,b1) + cosine vs sel. One wave per t-row; bf16 t reads.
__global__ __launch_bounds__(512) void k_finish(
    const unsigned short* __restrict__ tbuf,
    const float* __restrict__ g1, const float* __restrict__ b1,
    const float* __restrict__ sel, const float* __restrict__ selnorm,
    float* __restrict__ out)
{
    const int lane = threadIdx.x & 63;
    const int w = threadIdx.x >> 6;
    const int m = blockIdx.x * 8 + w;
    const int b = m >> 5;
    const uint2* t2  = (const uint2*)(tbuf + (size_t)m * HH);   // 4 bf16 per uint2
    const float4* g14 = (const float4*)g1;
    const float4* b14 = (const float4*)b1;
    const float4* s4  = (const float4*)(sel + (size_t)b * HH);

    float4 v4[3];
    float s = 0.f, q = 0.f;
#pragma unroll
    for (int j = 0; j < 3; ++j) {
        const uint2 a = t2[lane + 64 * j];
        v4[j].x = bf2f((unsigned short)(a.x & 0xFFFF));
        v4[j].y = bf2f((unsigned short)(a.x >> 16));
        v4[j].z = bf2f((unsigned short)(a.y & 0xFFFF));
        v4[j].w = bf2f((unsigned short)(a.y >> 16));
        s += (v4[j].x + v4[j].y) + (v4[j].z + v4[j].w);
        q = fmaf(v4[j].x, v4[j].x, q); q = fmaf(v4[j].y, v4[j].y, q);
        q = fmaf(v4[j].z, v4[j].z, q); q = fmaf(v4[j].w, v4[j].w, q);
    }
    for (int o = 32; o > 0; o >>= 1) {
        s += __shfl_xor(s, o, 64);
        q += __shfl_xor(q, o, 64);
    }
    const float mu = s * (1.0f / (float)HH);
    const float var = q * (1.0f / (float)HH) - mu * mu;
    const float rinv = rsqrtf(var + EPS_LN);

    float d = 0.f, n2 = 0.f;
#pragma unroll
    for (int j = 0; j < 3; ++j) {
        const int idx = lane + 64 * j;
        const float4 g = g14[idx];
        const float4 be = b14[idx];
        const float4 se = s4[idx];
        float y;
        y = (v4[j].x - mu) * rinv * g.x + be.x; d = fmaf(y, se.x, d); n2 = fmaf(y, y, n2);
        y = (v4[j].y - mu) * rinv * g.y + be.y; d = fmaf(y, se.y, d); n2 = fmaf(y, y, n2);
        y = (v4[j].z - mu) * rinv * g.z + be.z; d = fmaf(y, se.z, d); n2 = fmaf(y, y, n2);
        y = (v4[j].w - mu) * rinv * g.w + be.w; d = fmaf(y, se.w, d); n2 = fmaf(y, y, n2);
    }
    for (int o = 32; o > 0; o >>= 1) {
        d += __shfl_xor(d, o, 64);
        n2 += __shfl_xor(n2, o, 64);
    }
    if (lane == 0)
        out[m] = d / fmaxf(selnorm[b] * sqrtf(n2), EPS_COS);
}

extern "C" void kernel_launch(void* const* d_in, const int* in_sizes, int n_in,
                              void* d_out, int out_size, void* d_ws, size_t ws_size,
                              hipStream_t stream) {
    const float* hs  = (const float*)d_in[0];
    const float* gp  = (const float*)d_in[1];
    const float* W   = (const float*)d_in[2];
    const float* bia = (const float*)d_in[3];
    const float* g1  = (const float*)d_in[4];
    const float* b1  = (const float*)d_in[5];
    const float* g2  = (const float*)d_in[6];
    const float* b2  = (const float*)d_in[7];
    const int* gs    = (const int*)d_in[8];
    const int* ge    = (const int*)d_in[9];
    float* out = (float*)d_out;

    char* ws = (char*)d_ws;
    int4v* a_ws  = (int4v*)ws;                                          // 3.15 MB
    int4v* b_ws  = (int4v*)(ws + (size_t)A_RG * CH_PER_G * 16);         // 1.18 MB
    float* pp      = (float*)(ws + (size_t)(A_RG + B_RG) * CH_PER_G * 16); // 1.57 MB
    float* sel     = pp + (size_t)BB * SEG_SLICES * HH;                 // 196 KB
    float* selnorm = sel + (size_t)BB * HH;
    unsigned short* tbuf = (unsigned short*)(selnorm + BB);             // 3.15 MB bf16

    k_prep<<<SEG_BLK + A_RG + B_RG, 256, 0, stream>>>(gp, W, hs, gs, ge,
                                                      a_ws, b_ws, pp);
    k_gemm<<<NGB + BB, 128, 0, stream>>>(a_ws, b_ws, bia, pp, g2, b2, gs, ge,
                                         tbuf, sel, selnorm);
    k_finish<<<MM / 8, 512, 0, stream>>>(tbuf, g1, b1, sel, selnorm, out);
}